// Round 4
// baseline (236.925 us; speedup 1.0000x reference)
//
#include <hip/hip_runtime.h>

// LayerNorm over last dim W=256 for (B=8, C=128, H=128, W=256) fp32,
// then per-channel affine: out = (x - mean)/sqrt(var+eps) * gain[c] + bias[c].
//
// v6: persistent waves + depth-4 rotating register pipeline (copy-ubench
// structure). Session evidence: burst-MLP one-shot waves are anti-correlated
// with perf (v2 1-load ~69us < v4 4-load ~74 < v5 8-load ~80), while
// fill/copy ubenches hit 6.3-6.8 TB/s on this chip. Difference: SUSTAINED
// outstanding reads. Design rules learned from v3's failure:
//  - NO conditionals in the hot path (8192 waves x exactly 16 rows).
//  - Fully unrolled 16 static steps, 4 named slots (no runtime-indexed
//    register arrays -> no scratch).
//  - Reload the slot BEFORE the store of the current row, so counted
//    vmcnt waits never block on store acks (in-order vmcnt retirement).
//  - Strided rows (gw + 8192*i): grid sweeps one contiguous ~8MB window
//    per step. Channel parity alternates; gain/bias hoisted for both.
// Memory-bound: 268 MB total traffic, roofline ~43 us at 6.3 TB/s.

#define W_DIM 256
#define C_DIM 128
#define EPS 1e-8f

typedef float f32x4 __attribute__((ext_vector_type(4)));

#define NWAVES 8192
#define RPW    16          // rows per wave (131072 / 8192)

__global__ __launch_bounds__(256) void tLNv6_kernel(
    const float* __restrict__ inp,
    const float* __restrict__ gain,
    const float* __restrict__ bias,
    float* __restrict__ out,
    const int rows)
{
    const int lane = threadIdx.x & 63;
    const int gw   = (int)(blockIdx.x << 2) + (threadIdx.x >> 6);  // 0..8191

    const f32x4* __restrict__ in4  = (const f32x4*)inp;
    f32x4* __restrict__       out4 = (f32x4*)out;

    if (rows == NWAVES * RPW) {
        // ---- fixed-shape fast path: 16 rows, depth-4 pipeline ----
        // element address of step k: (gw + k*NWAVES)*64 + lane  (f32x4 units)
        const size_t base = (size_t)gw * 64 + lane;
        const size_t STEP = (size_t)NWAVES * 64;   // 524288 f32x4 per step

        // channel alternates between two values: c(k) = ((gw>>7) + 64k) & 127
        const int   c0 = (gw >> 7) & (C_DIM - 1);
        const int   c1 = (c0 + 64) & (C_DIM - 1);
        const float g0 = gain[c0], b0 = bias[c0];
        const float g1 = gain[c1], b1 = bias[c1];

        f32x4 s0 = in4[base];
        f32x4 s1 = in4[base + STEP];
        f32x4 s2 = in4[base + 2 * STEP];
        f32x4 s3 = in4[base + 3 * STEP];

        #define LN_STEP(k, s, gg, bb_)                                         \
        {                                                                      \
            float sum = (s.x + s.y) + (s.z + s.w);                             \
            float sq  = s.x * s.x;                                             \
            sq = fmaf(s.y, s.y, sq); sq = fmaf(s.z, s.z, sq);                  \
            sq = fmaf(s.w, s.w, sq);                                           \
            _Pragma("unroll")                                                  \
            for (int off = 1; off < 64; off <<= 1) {                           \
                sum += __shfl_xor(sum, off, 64);                               \
                sq  += __shfl_xor(sq,  off, 64);                               \
            }                                                                  \
            const float mean = sum * (1.0f / (float)W_DIM);                    \
            const float var  = sq * (1.0f / (float)W_DIM) - mean * mean;       \
            const float a    = rsqrtf(var + EPS) * gg;                         \
            const float bb   = bb_ - mean * a;                                 \
            f32x4 o;                                                           \
            o.x = fmaf(s.x, a, bb); o.y = fmaf(s.y, a, bb);                    \
            o.z = fmaf(s.z, a, bb); o.w = fmaf(s.w, a, bb);                    \
            if ((k) + 4 < RPW) s = in4[base + ((size_t)((k) + 4)) * STEP];     \
            __builtin_nontemporal_store(o, &out4[base + ((size_t)(k)) * STEP]);\
        }

        LN_STEP(0,  s0, g0, b0)
        LN_STEP(1,  s1, g1, b1)
        LN_STEP(2,  s2, g0, b0)
        LN_STEP(3,  s3, g1, b1)
        LN_STEP(4,  s0, g0, b0)
        LN_STEP(5,  s1, g1, b1)
        LN_STEP(6,  s2, g0, b0)
        LN_STEP(7,  s3, g1, b1)
        LN_STEP(8,  s0, g0, b0)
        LN_STEP(9,  s1, g1, b1)
        LN_STEP(10, s2, g0, b0)
        LN_STEP(11, s3, g1, b1)
        LN_STEP(12, s0, g0, b0)
        LN_STEP(13, s1, g1, b1)
        LN_STEP(14, s2, g0, b0)
        LN_STEP(15, s3, g1, b1)
        #undef LN_STEP
    } else {
        // ---- generic fallback (v2 structure): one row per wave iteration ----
        for (int row = gw; row < rows; row += NWAVES) {
            f32x4 v = in4[(size_t)row * 64 + lane];
            float sum = (v.x + v.y) + (v.z + v.w);
            float sq  = v.x * v.x;
            sq = fmaf(v.y, v.y, sq); sq = fmaf(v.z, v.z, sq);
            sq = fmaf(v.w, v.w, sq);
            #pragma unroll
            for (int off = 1; off < 64; off <<= 1) {
                sum += __shfl_xor(sum, off, 64);
                sq  += __shfl_xor(sq,  off, 64);
            }
            const float mean = sum * (1.0f / (float)W_DIM);
            const float var  = sq * (1.0f / (float)W_DIM) - mean * mean;
            const int   c    = (row >> 7) & (C_DIM - 1);
            const float a    = rsqrtf(var + EPS) * gain[c];
            const float bb   = bias[c] - mean * a;
            f32x4 o;
            o.x = fmaf(v.x, a, bb); o.y = fmaf(v.y, a, bb);
            o.z = fmaf(v.z, a, bb); o.w = fmaf(v.w, a, bb);
            out4[(size_t)row * 64 + lane] = o;
        }
    }
}

extern "C" void kernel_launch(void* const* d_in, const int* in_sizes, int n_in,
                              void* d_out, int out_size, void* d_ws, size_t ws_size,
                              hipStream_t stream)
{
    const float* inp  = (const float*)d_in[0];
    const float* gain = (const float*)d_in[1];
    const float* bias = (const float*)d_in[2];
    float* out = (float*)d_out;

    const int rows   = in_sizes[0] / W_DIM;   // 131072
    const int blocks = NWAVES / 4;            // 2048 blocks x 4 waves

    tLNv6_kernel<<<blocks, 256, 0, stream>>>(inp, gain, bias, out, rows);
}

// Round 6
// 221.731 us; speedup vs baseline: 1.0685x; 1.0685x over previous
//
#include <hip/hip_runtime.h>

// LayerNorm over last dim W=256 for (B=8, C=128, H=128, W=256) fp32,
// then per-channel affine: out = (x - mean)/sqrt(var+eps) * gain[c] + bias[c].
//
// v7 (re-run: round-5 bench died on container acquisition, not the kernel).
// v2's winning structure (1 row/wave, one-shot, plain loads/stores) with the
// cross-lane reduction moved OFF the LDS pipe onto the VALU.
//
// Why: every memory-side variant (MLP burst, persistence, prefetch depth,
// nt stores) landed at 65-84 us while fills hit 6.8 TB/s and float4 copy
// 6.3 TB/s on the same chip. VALUBusy 5-12%, conflicts 0, occupancy 57-65%
// with 32 resident waves/CU => per-wave latency is hidden; the limiter is a
// per-CU throughput resource. The only difference vs a copy kernel: 12
// __shfl_xor per row = 12 wave64 ds_bpermute on the LDS issue pipe
// (~8-15 cy each => ~100-180 cy/row vs the 160 cy/row budget at 6.3 TB/s).
//
// Fix: GCN DPP rotate-reduce (rocPRIM idiom), zero DS ops:
//   add(row_shr:1,2,4,8)  -> lane15 of each 16-lane row holds row sum
//   add(row_bcast15)      -> lane31 = rows0+1, lane63 = rows2+3
//   add(row_bcast31)      -> lane63 = full 64-lane sum
//   readlane(63)          -> wave-uniform scalar (SGPR), free broadcast
// 12 DPP VALU adds + 2 readlane per row replace 12 ds_bpermute.
// Memory-bound: 268 MB total traffic, roofline ~43 us at 6.3 TB/s.

#define W_DIM 256
#define C_DIM 128
#define EPS 1e-8f

typedef float f32x4 __attribute__((ext_vector_type(4)));

// x + dpp_move(x) with compile-time DPP control. bound_ctrl=true: lanes with
// no source get 0 (identity for add). row_mask=bank_mask=0xf (all lanes).
template <int CTRL>
__device__ __forceinline__ float dpp_add(float x)
{
    int moved = __builtin_amdgcn_update_dpp(
        0, __builtin_bit_cast(int, x), CTRL, 0xf, 0xf, true);
    return x + __builtin_bit_cast(float, moved);
}

__device__ __forceinline__ float read_lane63(float x)
{
    return __builtin_bit_cast(
        float, __builtin_amdgcn_readlane(__builtin_bit_cast(int, x), 63));
}

__global__ __launch_bounds__(256) void tLNv7_kernel(
    const float* __restrict__ inp,
    const float* __restrict__ gain,
    const float* __restrict__ bias,
    float* __restrict__ out,
    const int rows)
{
    const int lane = threadIdx.x & 63;
    const int row  = (int)(blockIdx.x << 2) + (threadIdx.x >> 6);  // 4 waves/blk
    if (row >= rows) return;

    const f32x4* __restrict__ in4  = (const f32x4*)inp;
    f32x4* __restrict__       out4 = (f32x4*)out;

    const size_t base = (size_t)row * 64 + lane;
    const f32x4 v = in4[base];

    // per-lane partials
    float s = (v.x + v.y) + (v.z + v.w);
    float q = v.x * v.x;
    q = fmaf(v.y, v.y, q); q = fmaf(v.z, v.z, q); q = fmaf(v.w, v.w, q);

    // ---- 64-lane reduction on the VALU pipe (no LDS ops) ----
    // interleaved s/q chains for ILP
    s = dpp_add<0x111>(s); q = dpp_add<0x111>(q);   // row_shr:1
    s = dpp_add<0x112>(s); q = dpp_add<0x112>(q);   // row_shr:2
    s = dpp_add<0x114>(s); q = dpp_add<0x114>(q);   // row_shr:4
    s = dpp_add<0x118>(s); q = dpp_add<0x118>(q);   // row_shr:8
    s = dpp_add<0x142>(s); q = dpp_add<0x142>(q);   // row_bcast15
    s = dpp_add<0x143>(s); q = dpp_add<0x143>(q);   // row_bcast31
    const float sum = read_lane63(s);
    const float sq  = read_lane63(q);

    const float mean = sum * (1.0f / (float)W_DIM);
    const float var  = sq  * (1.0f / (float)W_DIM) - mean * mean;

    // row -> channel: row = b*C*H + c*H + h, H=128 => c = (row>>7) & 127.
    // row is wave-uniform, so these are scalar loads.
    const int   c = (row >> 7) & (C_DIM - 1);
    const float a  = rsqrtf(var + EPS) * gain[c];
    const float bb = bias[c] - mean * a;

    f32x4 o;
    o.x = fmaf(v.x, a, bb); o.y = fmaf(v.y, a, bb);
    o.z = fmaf(v.z, a, bb); o.w = fmaf(v.w, a, bb);
    out4[base] = o;
}

extern "C" void kernel_launch(void* const* d_in, const int* in_sizes, int n_in,
                              void* d_out, int out_size, void* d_ws, size_t ws_size,
                              hipStream_t stream)
{
    const float* inp  = (const float*)d_in[0];
    const float* gain = (const float*)d_in[1];
    const float* bias = (const float*)d_in[2];
    float* out = (float*)d_out;

    const int rows   = in_sizes[0] / W_DIM;   // 131072
    const int blocks = (rows + 3) / 4;        // 4 waves/block -> 32768 blocks

    tLNv7_kernel<<<blocks, 256, 0, stream>>>(inp, gain, bias, out, rows);
}